// Round 3
// baseline (2112.274 us; speedup 1.0000x reference)
//
#include <hip/hip_runtime.h>
#include <stdint.h>

typedef __attribute__((ext_vector_type(8))) short shortx8;
typedef __attribute__((ext_vector_type(4))) float floatx4;

#define NR 16384      // nodes (M and K of the big GEMM)
#define DD 256        // feature dim
#define NSPLIT 4      // split-K factor
#define KCH (NR / NSPLIT)   // 4096
#define BK 32         // K tile per iteration
#define NIT (KCH / BK)      // 128
#define SB 40         // Bs row stride in ushorts (80 B = 5 x 16B chunks, 2-way banks = free)
#define SAS 40        // As row stride
#define SA 72         // k_lin LDS stride (unchanged from R2)

__device__ __forceinline__ unsigned short f2bf(float f) {
    union { float f; uint32_t u; } v; v.f = f;
    uint32_t u = v.u;
    return (unsigned short)((u + 0x7FFFu + ((u >> 16) & 1u)) >> 16);
}

// ---------------------------------------------------------------------------
// Kernel 0: x [16384][256] f32  ->  xT [256][16384] bf16   (transpose+convert)
// ---------------------------------------------------------------------------
__global__ __launch_bounds__(256) void k_xpose(const float* __restrict__ x,
                                               unsigned short* __restrict__ xT) {
    __shared__ unsigned short t[64][72];
    const int kb = blockIdx.x * 64;
    const int nb = blockIdx.y * 64;
    const int tid = threadIdx.x;
    const int lr = tid >> 4;
    const int lc = (tid & 15) * 4;
#pragma unroll
    for (int i = 0; i < 4; ++i) {
        const int k = kb + lr + 16 * i;
        const float4 v = *(const float4*)(x + (size_t)k * DD + nb + lc);
        t[lc + 0][lr + 16 * i] = f2bf(v.x);
        t[lc + 1][lr + 16 * i] = f2bf(v.y);
        t[lc + 2][lr + 16 * i] = f2bf(v.z);
        t[lc + 3][lr + 16 * i] = f2bf(v.w);
    }
    __syncthreads();
#pragma unroll
    for (int i = 0; i < 4; ++i) {
        const int nl = lr + 16 * i;
        ushort4 o;
        o.x = t[nl][lc + 0]; o.y = t[nl][lc + 1];
        o.z = t[nl][lc + 2]; o.w = t[nl][lc + 3];
        *(ushort4*)(xT + (size_t)(nb + nl) * NR + kb + lc) = o;
    }
}

// ---------------------------------------------------------------------------
// Kernel 1: agg_sum partials = adj @ x  (+ fused deg row-sums)
// Producer/consumer wave specialization: waves 0-3 stage (all vmem), waves
// 4-7 compute (no vmem in loop -> their pre-barrier vmcnt(0) is free).
// Double-buffered LDS, ONE barrier per BK=32 iteration.
// ---------------------------------------------------------------------------
__global__ __launch_bounds__(512, 2) void k_agg(const int* __restrict__ adj,
                                                const unsigned short* __restrict__ xT,
                                                float* __restrict__ aggP,
                                                float* __restrict__ degP) {
    __shared__ __align__(16) unsigned short Bs[2][256 * SB];  // 2 x 20480 B
    __shared__ __align__(16) unsigned short As[2][64 * SAS];  // 2 x  5120 B
    __shared__ int degs[64];

    const int tid  = threadIdx.x;
    const int wave = tid >> 6;
    const int lane = tid & 63;
    const int m0   = blockIdx.x * 64;
    const int kb0  = blockIdx.y * KCH;

    if (tid < 64) degs[tid] = 0;

    const bool prod = (wave < 4);

    // ---------------- producer state ----------------
    const int prow = tid >> 2;        // 0..63 (valid for producer tids 0..255)
    const int pc   = tid & 3;         // 0..3 -> k-cols pc*8 .. pc*8+7
    const int* apn = adj + (size_t)(m0 + prow) * NR + kb0 + pc * 8;
    const unsigned short* bg[5];
    {
#pragma unroll
        for (int j = 0; j < 5; ++j) {
            const int cid = (wave * 5 + j) * 64 + lane;   // 0..1279
            const int row = cid / 5;
            int sub = cid - row * 5; if (sub > 3) sub = 3; // pad chunk: dup, never read
            bg[j] = xT + (size_t)row * NR + kb0 + sub * 8;
        }
    }
    int4 ra[2][2];
    int dacc = 0;

    // ---------------- consumer state ----------------
    const int cw = wave - 4;
    const int q  = lane >> 4;
    const int ln = lane & 15;
    floatx4 acc[4][4] = {};

    // ---------------- prologue: stage iteration 0 into buf 0 ----------------
    if (prod) {
        // B(0) -> Bs[0]
#pragma unroll
        for (int j = 0; j < 5; ++j) {
            __builtin_amdgcn_global_load_lds(
                (const __attribute__((address_space(1))) void*)bg[j],
                (__attribute__((address_space(3))) void*)((char*)Bs[0] + (wave * 5 + j) * 1024),
                16, 0, 0);
            bg[j] += BK;
        }
        // adj(0) -> convert -> As[0]
        ra[0][0] = *(const int4*)(apn);
        ra[0][1] = *(const int4*)(apn + 4);
        {
            const int4 c0 = ra[0][0], c1 = ra[0][1];
            ushort4 w0, w1;
            w0.x = c0.x ? 0x3F80 : 0; w0.y = c0.y ? 0x3F80 : 0;
            w0.z = c0.z ? 0x3F80 : 0; w0.w = c0.w ? 0x3F80 : 0;
            w1.x = c1.x ? 0x3F80 : 0; w1.y = c1.y ? 0x3F80 : 0;
            w1.z = c1.z ? 0x3F80 : 0; w1.w = c1.w ? 0x3F80 : 0;
            *(ushort4*)&As[0][prow * SAS + pc * 8 + 0] = w0;
            *(ushort4*)&As[0][prow * SAS + pc * 8 + 4] = w1;
            dacc += c0.x + c0.y + c0.z + c0.w + c1.x + c1.y + c1.z + c1.w;
        }
        // prefetch adj(1)
        ra[1][0] = *(const int4*)(apn + BK);
        ra[1][1] = *(const int4*)(apn + BK + 4);
        apn += 2 * BK;   // points at adj(2)
    }
    __syncthreads();

    // ---------------- main loop: one barrier per iteration ----------------
    int buf = 0;
    for (int it = 0; it < NIT; ++it) {
        if (prod) {
            if (it + 1 < NIT) {
                const int nb = buf ^ 1;
                // B(it+1) -> Bs[nb]
#pragma unroll
                for (int j = 0; j < 5; ++j) {
                    __builtin_amdgcn_global_load_lds(
                        (const __attribute__((address_space(1))) void*)bg[j],
                        (__attribute__((address_space(3))) void*)((char*)Bs[nb] + (wave * 5 + j) * 1024),
                        16, 0, 0);
                    bg[j] += BK;
                }
                // convert adj(it+1) (regs loaded one body ago: latency hidden)
                const int rs = (it + 1) & 1;
                const int4 c0 = ra[rs][0], c1 = ra[rs][1];
                ushort4 w0, w1;
                w0.x = c0.x ? 0x3F80 : 0; w0.y = c0.y ? 0x3F80 : 0;
                w0.z = c0.z ? 0x3F80 : 0; w0.w = c0.w ? 0x3F80 : 0;
                w1.x = c1.x ? 0x3F80 : 0; w1.y = c1.y ? 0x3F80 : 0;
                w1.z = c1.z ? 0x3F80 : 0; w1.w = c1.w ? 0x3F80 : 0;
                *(ushort4*)&As[nb][prow * SAS + pc * 8 + 0] = w0;
                *(ushort4*)&As[nb][prow * SAS + pc * 8 + 4] = w1;
                dacc += c0.x + c0.y + c0.z + c0.w + c1.x + c1.y + c1.z + c1.w;
                // prefetch adj(it+2)
                if (it + 2 < NIT) {
                    ra[rs ^ 1][0] = *(const int4*)(apn);
                    ra[rs ^ 1][1] = *(const int4*)(apn + 4);
                    apn += BK;
                }
            }
        } else {
            // consumer: no vmem -> barrier vmcnt wait is free
            shortx8 af[4], bf[4];
#pragma unroll
            for (int mt = 0; mt < 4; ++mt)
                af[mt] = *(const shortx8*)&As[buf][(mt * 16 + ln) * SAS + q * 8];
#pragma unroll
            for (int nt = 0; nt < 4; ++nt)
                bf[nt] = *(const shortx8*)&Bs[buf][(cw * 64 + nt * 16 + ln) * SB + q * 8];
#pragma unroll
            for (int mt = 0; mt < 4; ++mt)
#pragma unroll
                for (int nt = 0; nt < 4; ++nt)
                    acc[mt][nt] = __builtin_amdgcn_mfma_f32_16x16x32_bf16(
                        af[mt], bf[nt], acc[mt][nt], 0, 0, 0);
        }
        __syncthreads();
        buf ^= 1;
    }

    // ---------------- epilogue ----------------
    if (prod) atomicAdd(&degs[prow], dacc);
    __syncthreads();
    if (tid < 64) degP[(size_t)blockIdx.y * NR + m0 + tid] = (float)degs[tid];

    if (!prod) {
        float* const outb = aggP + (size_t)blockIdx.y * NR * DD;
#pragma unroll
        for (int mt = 0; mt < 4; ++mt)
#pragma unroll
            for (int nt = 0; nt < 4; ++nt)
#pragma unroll
                for (int r = 0; r < 4; ++r) {
                    const int row = m0 + mt * 16 + q * 4 + r;
                    const int col = cw * 64 + nt * 16 + ln;
                    outb[(size_t)row * DD + col] = acc[mt][nt][r];
                }
    }
}

// ---------------------------------------------------------------------------
// Kernel 2: out = ((p0+p1+p2+p3)/deg) @ W^T + b    M=16384, N=256, K=256
// ---------------------------------------------------------------------------
__global__ __launch_bounds__(256, 2) void k_lin(const float* __restrict__ aggP,
                                                const float* __restrict__ degP,
                                                const float* __restrict__ W,
                                                const float* __restrict__ bias,
                                                float* __restrict__ out) {
    __shared__ __align__(16) unsigned short As[64 * SA];
    __shared__ __align__(16) unsigned short Bs[256 * SA];
    __shared__ float rdeg[64];
    __shared__ float bsh[256];

    const int tid  = threadIdx.x;
    const int wave = tid >> 6;
    const int lane = tid & 63;
    const int q    = lane >> 4;
    const int ln   = lane & 15;
    const int m0   = blockIdx.x * 64;

    if (tid < 64) {
        float d = 0.f;
#pragma unroll
        for (int s = 0; s < NSPLIT; ++s) d += degP[(size_t)s * NR + m0 + tid];
        rdeg[tid] = 1.0f / d;
    }
    bsh[tid] = bias[tid];

    const int arow = tid >> 4;
    const int acol = (tid & 15) * 4;

    floatx4 acc[4][4] = {};

    for (int it = 0; it < 4; ++it) {
        const int kb = it * 64;
        __syncthreads();

#pragma unroll
        for (int i = 0; i < 4; ++i) {
            const int r = arow + 16 * i;
            const size_t g = (size_t)(m0 + r) * DD + kb + acol;
            float4 p = *(const float4*)(aggP + g);
#pragma unroll
            for (int s = 1; s < NSPLIT; ++s) {
                const float4 ps = *(const float4*)(aggP + (size_t)s * NR * DD + g);
                p.x += ps.x; p.y += ps.y; p.z += ps.z; p.w += ps.w;
            }
            const float sc = rdeg[r];
            ushort4 o;
            o.x = f2bf(p.x * sc);
            o.y = f2bf(p.y * sc);
            o.z = f2bf(p.z * sc);
            o.w = f2bf(p.w * sc);
            *(ushort4*)&As[r * SA + acol] = o;
        }
#pragma unroll
        for (int i = 0; i < 16; ++i) {
            const int r = arow + 16 * i;
            const float4 w4 = *(const float4*)(W + (size_t)r * DD + kb + acol);
            ushort4 o;
            o.x = f2bf(w4.x); o.y = f2bf(w4.y);
            o.z = f2bf(w4.z); o.w = f2bf(w4.w);
            *(ushort4*)&Bs[r * SA + acol] = o;
        }
        __syncthreads();

#pragma unroll
        for (int ks = 0; ks < 2; ++ks) {
            const int kk = ks * 32 + q * 8;
            shortx8 af[4], bf[4];
#pragma unroll
            for (int mt = 0; mt < 4; ++mt)
                af[mt] = *(const shortx8*)&As[(mt * 16 + ln) * SA + kk];
#pragma unroll
            for (int nt = 0; nt < 4; ++nt)
                bf[nt] = *(const shortx8*)&Bs[(wave * 64 + nt * 16 + ln) * SA + kk];
#pragma unroll
            for (int mt = 0; mt < 4; ++mt)
#pragma unroll
                for (int nt = 0; nt < 4; ++nt)
                    acc[mt][nt] = __builtin_amdgcn_mfma_f32_16x16x32_bf16(
                        af[mt], bf[nt], acc[mt][nt], 0, 0, 0);
        }
    }

#pragma unroll
    for (int mt = 0; mt < 4; ++mt)
#pragma unroll
        for (int nt = 0; nt < 4; ++nt)
#pragma unroll
            for (int r = 0; r < 4; ++r) {
                const int row = m0 + mt * 16 + q * 4 + r;
                const int col = wave * 64 + nt * 16 + ln;
                out[(size_t)row * DD + col] = acc[mt][nt][r] + bsh[col];
            }
}

// ---------------------------------------------------------------------------
extern "C" void kernel_launch(void* const* d_in, const int* in_sizes, int n_in,
                              void* d_out, int out_size, void* d_ws, size_t ws_size,
                              hipStream_t stream) {
    const float* x    = (const float*)d_in[0];
    const int*   adj  = (const int*)d_in[1];
    const float* W    = (const float*)d_in[2];
    const float* bias = (const float*)d_in[3];
    float* out = (float*)d_out;

    // ws layout: xT bf16 8 MB | aggP fp32 NSPLIT x 16 MB | degP fp32 NSPLIT x 64 KB
    unsigned short* xT  = (unsigned short*)d_ws;
    float* aggP = (float*)((char*)d_ws + (size_t)8 * 1024 * 1024);
    float* degP = (float*)((char*)d_ws + (size_t)(8 + 16 * NSPLIT) * 1024 * 1024);

    k_xpose<<<dim3(NR / 64, DD / 64), 256, 0, stream>>>(x, xT);
    k_agg<<<dim3(NR / 64, NSPLIT), 512, 0, stream>>>(adj, xT, aggP, degP);
    k_lin<<<dim3(NR / 64), 256, 0, stream>>>(aggP, degP, W, bias, out);
}

// Round 4
// 1588.526 us; speedup vs baseline: 1.3297x; 1.3297x over previous
//
#include <hip/hip_runtime.h>
#include <stdint.h>

typedef __attribute__((ext_vector_type(8))) short shortx8;
typedef __attribute__((ext_vector_type(4))) float floatx4;

#define NR 16384      // nodes (M and K of the big GEMM)
#define DD 256        // feature dim
#define NSPLIT 4      // split-K factor
#define KCH (NR / NSPLIT)   // 4096
#define BK 32         // K per iteration
#define NIT (KCH / BK)      // 128
#define SA 72         // k_lin LDS stride

__device__ __forceinline__ unsigned short f2bf(float f) {
    union { float f; uint32_t u; } v; v.f = f;
    uint32_t u = v.u;
    return (unsigned short)((u + 0x7FFFu + ((u >> 16) & 1u)) >> 16);
}

// ---------------------------------------------------------------------------
// Kernel 0: x [16384][256] f32  ->  xT [256][16384] bf16   (transpose+convert)
// ---------------------------------------------------------------------------
__global__ __launch_bounds__(256) void k_xpose(const float* __restrict__ x,
                                               unsigned short* __restrict__ xT) {
    __shared__ unsigned short t[64][72];
    const int kb = blockIdx.x * 64;
    const int nb = blockIdx.y * 64;
    const int tid = threadIdx.x;
    const int lr = tid >> 4;
    const int lc = (tid & 15) * 4;
#pragma unroll
    for (int i = 0; i < 4; ++i) {
        const int k = kb + lr + 16 * i;
        const float4 v = *(const float4*)(x + (size_t)k * DD + nb + lc);
        t[lc + 0][lr + 16 * i] = f2bf(v.x);
        t[lc + 1][lr + 16 * i] = f2bf(v.y);
        t[lc + 2][lr + 16 * i] = f2bf(v.z);
        t[lc + 3][lr + 16 * i] = f2bf(v.w);
    }
    __syncthreads();
#pragma unroll
    for (int i = 0; i < 4; ++i) {
        const int nl = lr + 16 * i;
        ushort4 o;
        o.x = t[nl][lc + 0]; o.y = t[nl][lc + 1];
        o.z = t[nl][lc + 2]; o.w = t[nl][lc + 3];
        *(ushort4*)(xT + (size_t)(nb + nl) * NR + kb + lc) = o;
    }
}

// ---------------------------------------------------------------------------
// Kernel 1: agg partials = adj @ x (+ fused deg row-sums)
// Single-barrier double-buffered K-loop: stage(it+1) issued at TOP of body
// (right after the barrier), consume(it) fills the body, barrier at BOTTOM.
// The pre-barrier vmcnt(0) drain thus lands a full compute-phase after issue
// -> it throttles to HBM BW instead of serializing on load latency.
// adj staged RAW int32 -> LDS via global_load_lds (XOR-swizzled chunks),
// converted to bf16 per-fragment in registers.  256 thr, tile 64x256, BK=32.
// ---------------------------------------------------------------------------
__global__ __launch_bounds__(256, 3) void k_agg(const int* __restrict__ adj,
                                                const unsigned short* __restrict__ xT,
                                                float* __restrict__ aggP,
                                                float* __restrict__ degP) {
    // AsI: 64 rows x 32 ints (128 B/row = 8 chunks of 16 B), chunk pp holds
    //      global part p = pp ^ (row & 7)  -> conflict-free frag reads.
    // Bs : 256 rows x 32 bf16 (64 B/row), linear -> naturally conflict-free.
    __shared__ __align__(16) int            AsI[2][64 * 32];    // 2 x  8 KB
    __shared__ __align__(16) unsigned short Bs [2][256 * 32];   // 2 x 16 KB
    __shared__ int degs[64];

    const int tid  = threadIdx.x;
    const int wave = tid >> 6;
    const int lane = tid & 63;
    const int q    = lane >> 4;       // quad 0..3
    const int ln   = lane & 15;
    const int m0   = blockIdx.x * 64;
    const int kb0  = blockIdx.y * KCH;

    if (tid < 64) degs[tid] = 0;

    // ---- staging source pointers (2 A-instrs + 4 B-instrs per wave) ----
    const int* srcA[2];
#pragma unroll
    for (int j = 0; j < 2; ++j) {
        const int L = (wave * 2 + j) * 64 + lane;   // chunk id 0..511
        const int r = L >> 3;                        // adj row 0..63
        const int pp = L & 7;                        // LDS chunk pos in row
        const int p  = pp ^ (r & 7);                 // global 16B part
        srcA[j] = adj + (size_t)(m0 + r) * NR + kb0 + p * 4;
    }
    const unsigned short* srcB[4];
#pragma unroll
    for (int j = 0; j < 4; ++j) {
        const int L = (wave * 4 + j) * 64 + lane;   // chunk id 0..1023
        const int n = L >> 2;                        // xT row 0..255
        const int pb = L & 3;                        // 16B part in row
        srcB[j] = xT + (size_t)n * NR + kb0 + pb * 8;
    }

    floatx4 acc[4][4] = {};
    int dacc[4] = {0, 0, 0, 0};

    const int pp0 = (2 * q) ^ (ln & 7);   // LDS pos of global part 2q (row&7 == ln&7)
    const int pp1 = pp0 ^ 1;              // LDS pos of global part 2q+1

    // ---- prologue: stage it=0 into buf 0 ----
#pragma unroll
    for (int j = 0; j < 2; ++j) {
        __builtin_amdgcn_global_load_lds(
            (const __attribute__((address_space(1))) void*)srcA[j],
            (__attribute__((address_space(3))) void*)(AsI[0] + (wave * 2 + j) * 256),
            16, 0, 0);
        srcA[j] += BK;
    }
#pragma unroll
    for (int j = 0; j < 4; ++j) {
        __builtin_amdgcn_global_load_lds(
            (const __attribute__((address_space(1))) void*)srcB[j],
            (__attribute__((address_space(3))) void*)(Bs[0] + (wave * 4 + j) * 512),
            16, 0, 0);
        srcB[j] += BK;
    }
    __syncthreads();

    int buf = 0;
    for (int it = 0; it < NIT; ++it) {
        // ---- TOP: issue stage(it+1) into the other buffer ----
        if (it + 1 < NIT) {
            const int nb = buf ^ 1;
#pragma unroll
            for (int j = 0; j < 2; ++j) {
                __builtin_amdgcn_global_load_lds(
                    (const __attribute__((address_space(1))) void*)srcA[j],
                    (__attribute__((address_space(3))) void*)(AsI[nb] + (wave * 2 + j) * 256),
                    16, 0, 0);
                srcA[j] += BK;
            }
#pragma unroll
            for (int j = 0; j < 4; ++j) {
                __builtin_amdgcn_global_load_lds(
                    (const __attribute__((address_space(1))) void*)srcB[j],
                    (__attribute__((address_space(3))) void*)(Bs[nb] + (wave * 4 + j) * 512),
                    16, 0, 0);
                srcB[j] += BK;
            }
        }

        // ---- consume buf: read A ints, convert, read B, 16 MFMA ----
        shortx8 af[4], bf[4];
#pragma unroll
        for (int mt = 0; mt < 4; ++mt) {
            const int* base = &AsI[buf][(mt * 16 + ln) * 32];
            const int4 c0 = *(const int4*)(base + pp0 * 4);  // k = q*8 .. q*8+3
            const int4 c1 = *(const int4*)(base + pp1 * 4);  // k = q*8+4 .. q*8+7
            union { shortx8 v; uint32_t u[4]; } A;
            A.u[0] = (c0.x ? 0x3F80u : 0u) | (c0.y ? 0x3F800000u : 0u);
            A.u[1] = (c0.z ? 0x3F80u : 0u) | (c0.w ? 0x3F800000u : 0u);
            A.u[2] = (c1.x ? 0x3F80u : 0u) | (c1.y ? 0x3F800000u : 0u);
            A.u[3] = (c1.z ? 0x3F80u : 0u) | (c1.w ? 0x3F800000u : 0u);
            af[mt] = A.v;
            if (wave == 0)  // only one wave counts (A frags identical across waves)
                dacc[mt] += c0.x + c0.y + c0.z + c0.w + c1.x + c1.y + c1.z + c1.w;
        }
#pragma unroll
        for (int nt = 0; nt < 4; ++nt)
            bf[nt] = *(const shortx8*)&Bs[buf][(wave * 64 + nt * 16 + ln) * 32 + q * 8];
#pragma unroll
        for (int mt = 0; mt < 4; ++mt)
#pragma unroll
            for (int nt = 0; nt < 4; ++nt)
                acc[mt][nt] = __builtin_amdgcn_mfma_f32_16x16x32_bf16(
                    af[mt], bf[nt], acc[mt][nt], 0, 0, 0);

        // ---- BOTTOM: one barrier (drain overlapped by the body above) ----
        __syncthreads();
        buf ^= 1;
    }

    // ---- deg reduce + write ----
    if (wave == 0) {
#pragma unroll
        for (int mt = 0; mt < 4; ++mt)
            atomicAdd(&degs[mt * 16 + ln], dacc[mt]);
    }
    __syncthreads();
    if (tid < 64) degP[(size_t)blockIdx.y * NR + m0 + tid] = (float)degs[tid];

    // ---- acc writeback (C/D layout: col=ln, row=q*4+r) ----
    float* const outb = aggP + (size_t)blockIdx.y * NR * DD;
#pragma unroll
    for (int mt = 0; mt < 4; ++mt)
#pragma unroll
        for (int nt = 0; nt < 4; ++nt)
#pragma unroll
            for (int r = 0; r < 4; ++r) {
                const int row = m0 + mt * 16 + q * 4 + r;
                const int col = wave * 64 + nt * 16 + ln;
                outb[(size_t)row * DD + col] = acc[mt][nt][r];
            }
}

// ---------------------------------------------------------------------------
// Kernel 2: out = ((p0+p1+p2+p3)/deg) @ W^T + b    M=16384, N=256, K=256
// ---------------------------------------------------------------------------
__global__ __launch_bounds__(256, 2) void k_lin(const float* __restrict__ aggP,
                                                const float* __restrict__ degP,
                                                const float* __restrict__ W,
                                                const float* __restrict__ bias,
                                                float* __restrict__ out) {
    __shared__ __align__(16) unsigned short As[64 * SA];
    __shared__ __align__(16) unsigned short Bs[256 * SA];
    __shared__ float rdeg[64];
    __shared__ float bsh[256];

    const int tid  = threadIdx.x;
    const int wave = tid >> 6;
    const int lane = tid & 63;
    const int q    = lane >> 4;
    const int ln   = lane & 15;
    const int m0   = blockIdx.x * 64;

    if (tid < 64) {
        float d = 0.f;
#pragma unroll
        for (int s = 0; s < NSPLIT; ++s) d += degP[(size_t)s * NR + m0 + tid];
        rdeg[tid] = 1.0f / d;
    }
    bsh[tid] = bias[tid];

    const int arow = tid >> 4;
    const int acol = (tid & 15) * 4;

    floatx4 acc[4][4] = {};

    for (int it = 0; it < 4; ++it) {
        const int kb = it * 64;
        __syncthreads();

#pragma unroll
        for (int i = 0; i < 4; ++i) {
            const int r = arow + 16 * i;
            const size_t g = (size_t)(m0 + r) * DD + kb + acol;
            float4 p = *(const float4*)(aggP + g);
#pragma unroll
            for (int s = 1; s < NSPLIT; ++s) {
                const float4 ps = *(const float4*)(aggP + (size_t)s * NR * DD + g);
                p.x += ps.x; p.y += ps.y; p.z += ps.z; p.w += ps.w;
            }
            const float sc = rdeg[r];
            ushort4 o;
            o.x = f2bf(p.x * sc);
            o.y = f2bf(p.y * sc);
            o.z = f2bf(p.z * sc);
            o.w = f2bf(p.w * sc);
            *(ushort4*)&As[r * SA + acol] = o;
        }
#pragma unroll
        for (int i = 0; i < 16; ++i) {
            const int r = arow + 16 * i;
            const float4 w4 = *(const float4*)(W + (size_t)r * DD + kb + acol);
            ushort4 o;
            o.x = f2bf(w4.x); o.y = f2bf(w4.y);
            o.z = f2bf(w4.z); o.w = f2bf(w4.w);
            *(ushort4*)&Bs[r * SA + acol] = o;
        }
        __syncthreads();

#pragma unroll
        for (int ks = 0; ks < 2; ++ks) {
            const int kk = ks * 32 + q * 8;
            shortx8 af[4], bf[4];
#pragma unroll
            for (int mt = 0; mt < 4; ++mt)
                af[mt] = *(const shortx8*)&As[(mt * 16 + ln) * SA + kk];
#pragma unroll
            for (int nt = 0; nt < 4; ++nt)
                bf[nt] = *(const shortx8*)&Bs[(wave * 64 + nt * 16 + ln) * SA + kk];
#pragma unroll
            for (int mt = 0; mt < 4; ++mt)
#pragma unroll
                for (int nt = 0; nt < 4; ++nt)
                    acc[mt][nt] = __builtin_amdgcn_mfma_f32_16x16x32_bf16(
                        af[mt], bf[nt], acc[mt][nt], 0, 0, 0);
        }
    }

#pragma unroll
    for (int mt = 0; mt < 4; ++mt)
#pragma unroll
        for (int nt = 0; nt < 4; ++nt)
#pragma unroll
            for (int r = 0; r < 4; ++r) {
                const int row = m0 + mt * 16 + q * 4 + r;
                const int col = wave * 64 + nt * 16 + ln;
                out[(size_t)row * DD + col] = acc[mt][nt][r] + bsh[col];
            }
}

// ---------------------------------------------------------------------------
extern "C" void kernel_launch(void* const* d_in, const int* in_sizes, int n_in,
                              void* d_out, int out_size, void* d_ws, size_t ws_size,
                              hipStream_t stream) {
    const float* x    = (const float*)d_in[0];
    const int*   adj  = (const int*)d_in[1];
    const float* W    = (const float*)d_in[2];
    const float* bias = (const float*)d_in[3];
    float* out = (float*)d_out;

    // ws layout: xT bf16 8 MB | aggP fp32 NSPLIT x 16 MB | degP fp32 NSPLIT x 64 KB
    unsigned short* xT  = (unsigned short*)d_ws;
    float* aggP = (float*)((char*)d_ws + (size_t)8 * 1024 * 1024);
    float* degP = (float*)((char*)d_ws + (size_t)(8 + 16 * NSPLIT) * 1024 * 1024);

    k_xpose<<<dim3(NR / 64, DD / 64), 256, 0, stream>>>(x, xT);
    k_agg<<<dim3(NR / 64, NSPLIT), 256, 0, stream>>>(adj, xT, aggP, degP);
    k_lin<<<dim3(NR / 64), 256, 0, stream>>>(aggP, degP, W, bias, out);
}

// Round 5
// 1508.945 us; speedup vs baseline: 1.3998x; 1.0527x over previous
//
#include <hip/hip_runtime.h>
#include <stdint.h>

typedef __attribute__((ext_vector_type(8))) short shortx8;
typedef __attribute__((ext_vector_type(4))) float floatx4;

#define NR 16384      // nodes (M and K of the big GEMM)
#define DD 256        // feature dim
#define NSPLIT 2      // split-K factor
#define KCH (NR / NSPLIT)   // 8192
#define BK 32         // K per iteration
#define NIT (KCH / BK)      // 256
#define SA 72         // k_lin LDS stride

// s_waitcnt simm16: vmcnt[3:0]=simm[3:0], expcnt=simm[6:4], lgkmcnt=simm[11:8], vmcnt[5:4]=simm[15:14]
#define WAIT_VM6 0x0F76   // vmcnt(6), lgkm/exp unconstrained
#define WAIT_VM0 0x0F70   // vmcnt(0), lgkm/exp unconstrained

__device__ __forceinline__ unsigned short f2bf(float f) {
    union { float f; uint32_t u; } v; v.f = f;
    uint32_t u = v.u;
    return (unsigned short)((u + 0x7FFFu + ((u >> 16) & 1u)) >> 16);
}

// ---------------------------------------------------------------------------
// Kernel 0: x [16384][256] f32  ->  xT [256][16384] bf16   (transpose+convert)
// ---------------------------------------------------------------------------
__global__ __launch_bounds__(256) void k_xpose(const float* __restrict__ x,
                                               unsigned short* __restrict__ xT) {
    __shared__ unsigned short t[64][72];
    const int kb = blockIdx.x * 64;
    const int nb = blockIdx.y * 64;
    const int tid = threadIdx.x;
    const int lr = tid >> 4;
    const int lc = (tid & 15) * 4;
#pragma unroll
    for (int i = 0; i < 4; ++i) {
        const int k = kb + lr + 16 * i;
        const float4 v = *(const float4*)(x + (size_t)k * DD + nb + lc);
        t[lc + 0][lr + 16 * i] = f2bf(v.x);
        t[lc + 1][lr + 16 * i] = f2bf(v.y);
        t[lc + 2][lr + 16 * i] = f2bf(v.z);
        t[lc + 3][lr + 16 * i] = f2bf(v.w);
    }
    __syncthreads();
#pragma unroll
    for (int i = 0; i < 4; ++i) {
        const int nl = lr + 16 * i;
        ushort4 o;
        o.x = t[nl][lc + 0]; o.y = t[nl][lc + 1];
        o.z = t[nl][lc + 2]; o.w = t[nl][lc + 3];
        *(ushort4*)(xT + (size_t)(nb + nl) * NR + kb + lc) = o;
    }
}

// ---------------------------------------------------------------------------
// Kernel 1: agg partials = adj @ x (+ fused deg row-sums)
// 3-stage software pipeline, AITER-style: stage(it+2) issued at bottom of
// iter it; top of iter waits s_waitcnt vmcnt(6) (drains stage(it), leaves
// stage(it+1)'s 6 loads in flight) + raw s_barrier. HBM queue never empties.
// All 4 waves issue exactly 6 global_load_lds per iter (uniform vmcnt FIFO).
// adj staged raw int32, XOR-swizzled 16B chunks; converted per-fragment.
// ---------------------------------------------------------------------------
__global__ __launch_bounds__(256, 2) void k_agg(const int* __restrict__ adj,
                                                const unsigned short* __restrict__ xT,
                                                float* __restrict__ aggP,
                                                float* __restrict__ degP) {
    __shared__ __align__(16) int            AsI[3][64 * 32];    // 3 x  8 KB
    __shared__ __align__(16) unsigned short Bs [3][256 * 32];   // 3 x 16 KB
    __shared__ int degs[64];

    const int tid  = threadIdx.x;
    const int wave = tid >> 6;
    const int lane = tid & 63;
    const int q    = lane >> 4;       // quad 0..3
    const int ln   = lane & 15;
    const int m0   = blockIdx.x * 64;
    const int kb0  = blockIdx.y * KCH;

    if (tid < 64) degs[tid] = 0;

    // ---- staging source pointers (2 A-instrs + 4 B-instrs per wave) ----
    const int* srcA[2];
#pragma unroll
    for (int j = 0; j < 2; ++j) {
        const int L = (wave * 2 + j) * 64 + lane;   // chunk id 0..511
        const int r = L >> 3;                        // adj row 0..63
        const int pp = L & 7;                        // LDS chunk pos in row
        const int p  = pp ^ (r & 7);                 // global 16B part
        srcA[j] = adj + (size_t)(m0 + r) * NR + kb0 + p * 4;
    }
    const unsigned short* srcB[4];
#pragma unroll
    for (int j = 0; j < 4; ++j) {
        const int L = (wave * 4 + j) * 64 + lane;   // chunk id 0..1023
        const int n = L >> 2;                        // xT row 0..255
        const int pb = L & 3;                        // 16B part in row
        srcB[j] = xT + (size_t)n * NR + kb0 + pb * 8;
    }

    floatx4 acc[4][4] = {};
    int dacc[4] = {0, 0, 0, 0};

    const int pp0 = (2 * q) ^ (ln & 7);   // LDS pos of global part 2q
    const int pp1 = pp0 ^ 1;              // LDS pos of global part 2q+1

    // ---- prologue: stage it=0 -> buf0, it=1 -> buf1 (12 loads in flight) ----
#pragma unroll
    for (int s = 0; s < 2; ++s) {
#pragma unroll
        for (int j = 0; j < 2; ++j) {
            __builtin_amdgcn_global_load_lds(
                (const __attribute__((address_space(1))) void*)srcA[j],
                (__attribute__((address_space(3))) void*)(AsI[s] + (wave * 2 + j) * 256),
                16, 0, 0);
            srcA[j] += BK;
        }
#pragma unroll
        for (int j = 0; j < 4; ++j) {
            __builtin_amdgcn_global_load_lds(
                (const __attribute__((address_space(1))) void*)srcB[j],
                (__attribute__((address_space(3))) void*)(Bs[s] + (wave * 4 + j) * 512),
                16, 0, 0);
            srcB[j] += BK;
        }
    }

    int cb = 0;                 // consume buffer
    int sb = 2;                 // stage buffer (it+2)
    for (int it = 0; it < NIT; ++it) {
        // ---- TOP: ensure stage(it) landed; join waves ----
        if (it + 1 < NIT) __builtin_amdgcn_s_waitcnt(WAIT_VM6);
        else              __builtin_amdgcn_s_waitcnt(WAIT_VM0);
        __builtin_amdgcn_s_barrier();

        // ---- consume buf cb: read A ints, convert, read B, 16 MFMA ----
        shortx8 af[4], bf[4];
#pragma unroll
        for (int mt = 0; mt < 4; ++mt) {
            const int* base = &AsI[cb][(mt * 16 + ln) * 32];
            const int4 c0 = *(const int4*)(base + pp0 * 4);  // k = q*8 .. q*8+3
            const int4 c1 = *(const int4*)(base + pp1 * 4);  // k = q*8+4 .. q*8+7
            union { shortx8 v; uint32_t u[4]; } A;
            A.u[0] = (c0.x ? 0x3F80u : 0u) | (c0.y ? 0x3F800000u : 0u);
            A.u[1] = (c0.z ? 0x3F80u : 0u) | (c0.w ? 0x3F800000u : 0u);
            A.u[2] = (c1.x ? 0x3F80u : 0u) | (c1.y ? 0x3F800000u : 0u);
            A.u[3] = (c1.z ? 0x3F80u : 0u) | (c1.w ? 0x3F800000u : 0u);
            af[mt] = A.v;
            if (wave == 0)  // one wave counts (A frags identical across waves)
                dacc[mt] += c0.x + c0.y + c0.z + c0.w + c1.x + c1.y + c1.z + c1.w;
        }
#pragma unroll
        for (int nt = 0; nt < 4; ++nt)
            bf[nt] = *(const shortx8*)&Bs[cb][(wave * 64 + nt * 16 + ln) * 32 + q * 8];
#pragma unroll
        for (int mt = 0; mt < 4; ++mt)
#pragma unroll
            for (int nt = 0; nt < 4; ++nt)
                acc[mt][nt] = __builtin_amdgcn_mfma_f32_16x16x32_bf16(
                    af[mt], bf[nt], acc[mt][nt], 0, 0, 0);

        // ---- BOTTOM: issue stage(it+2) into sb (lands >=900cyc from now) ----
        if (it + 2 < NIT) {
#pragma unroll
            for (int j = 0; j < 2; ++j) {
                __builtin_amdgcn_global_load_lds(
                    (const __attribute__((address_space(1))) void*)srcA[j],
                    (__attribute__((address_space(3))) void*)(AsI[sb] + (wave * 2 + j) * 256),
                    16, 0, 0);
                srcA[j] += BK;
            }
#pragma unroll
            for (int j = 0; j < 4; ++j) {
                __builtin_amdgcn_global_load_lds(
                    (const __attribute__((address_space(1))) void*)srcB[j],
                    (__attribute__((address_space(3))) void*)(Bs[sb] + (wave * 4 + j) * 512),
                    16, 0, 0);
                srcB[j] += BK;
            }
        }
        cb = (cb == 2) ? 0 : cb + 1;
        sb = (sb == 2) ? 0 : sb + 1;
    }

    // ---- deg reduce + write ----
    if (wave == 0) {
#pragma unroll
        for (int mt = 0; mt < 4; ++mt)
            atomicAdd(&degs[mt * 16 + ln], dacc[mt]);
    }
    __syncthreads();
    if (tid < 64) degP[(size_t)blockIdx.y * NR + m0 + tid] = (float)degs[tid];

    // ---- acc writeback (C/D layout: col=ln, row=q*4+r) ----
    float* const outb = aggP + (size_t)blockIdx.y * NR * DD;
#pragma unroll
    for (int mt = 0; mt < 4; ++mt)
#pragma unroll
        for (int nt = 0; nt < 4; ++nt)
#pragma unroll
            for (int r = 0; r < 4; ++r) {
                const int row = m0 + mt * 16 + q * 4 + r;
                const int col = wave * 64 + nt * 16 + ln;
                outb[(size_t)row * DD + col] = acc[mt][nt][r];
            }
}

// ---------------------------------------------------------------------------
// Kernel 2: out = ((p0+p1)/deg) @ W^T + b    M=16384, N=256, K=256
// ---------------------------------------------------------------------------
__global__ __launch_bounds__(256, 2) void k_lin(const float* __restrict__ aggP,
                                                const float* __restrict__ degP,
                                                const float* __restrict__ W,
                                                const float* __restrict__ bias,
                                                float* __restrict__ out) {
    __shared__ __align__(16) unsigned short As[64 * SA];
    __shared__ __align__(16) unsigned short Bs[256 * SA];
    __shared__ float rdeg[64];
    __shared__ float bsh[256];

    const int tid  = threadIdx.x;
    const int wave = tid >> 6;
    const int lane = tid & 63;
    const int q    = lane >> 4;
    const int ln   = lane & 15;
    const int m0   = blockIdx.x * 64;

    if (tid < 64) {
        float d = 0.f;
#pragma unroll
        for (int s = 0; s < NSPLIT; ++s) d += degP[(size_t)s * NR + m0 + tid];
        rdeg[tid] = 1.0f / d;
    }
    bsh[tid] = bias[tid];

    const int arow = tid >> 4;
    const int acol = (tid & 15) * 4;

    floatx4 acc[4][4] = {};

    for (int it = 0; it < 4; ++it) {
        const int kb = it * 64;
        __syncthreads();

#pragma unroll
        for (int i = 0; i < 4; ++i) {
            const int r = arow + 16 * i;
            const size_t g = (size_t)(m0 + r) * DD + kb + acol;
            float4 p = *(const float4*)(aggP + g);
#pragma unroll
            for (int s = 1; s < NSPLIT; ++s) {
                const float4 ps = *(const float4*)(aggP + (size_t)s * NR * DD + g);
                p.x += ps.x; p.y += ps.y; p.z += ps.z; p.w += ps.w;
            }
            const float sc = rdeg[r];
            ushort4 o;
            o.x = f2bf(p.x * sc);
            o.y = f2bf(p.y * sc);
            o.z = f2bf(p.z * sc);
            o.w = f2bf(p.w * sc);
            *(ushort4*)&As[r * SA + acol] = o;
        }
#pragma unroll
        for (int i = 0; i < 16; ++i) {
            const int r = arow + 16 * i;
            const float4 w4 = *(const float4*)(W + (size_t)r * DD + kb + acol);
            ushort4 o;
            o.x = f2bf(w4.x); o.y = f2bf(w4.y);
            o.z = f2bf(w4.z); o.w = f2bf(w4.w);
            *(ushort4*)&Bs[r * SA + acol] = o;
        }
        __syncthreads();

#pragma unroll
        for (int ks = 0; ks < 2; ++ks) {
            const int kk = ks * 32 + q * 8;
            shortx8 af[4], bf[4];
#pragma unroll
            for (int mt = 0; mt < 4; ++mt)
                af[mt] = *(const shortx8*)&As[(mt * 16 + ln) * SA + kk];
#pragma unroll
            for (int nt = 0; nt < 4; ++nt)
                bf[nt] = *(const shortx8*)&Bs[(wave * 64 + nt * 16 + ln) * SA + kk];
#pragma unroll
            for (int mt = 0; mt < 4; ++mt)
#pragma unroll
                for (int nt = 0; nt < 4; ++nt)
                    acc[mt][nt] = __builtin_amdgcn_mfma_f32_16x16x32_bf16(
                        af[mt], bf[nt], acc[mt][nt], 0, 0, 0);
        }
    }

#pragma unroll
    for (int mt = 0; mt < 4; ++mt)
#pragma unroll
        for (int nt = 0; nt < 4; ++nt)
#pragma unroll
            for (int r = 0; r < 4; ++r) {
                const int row = m0 + mt * 16 + q * 4 + r;
                const int col = wave * 64 + nt * 16 + ln;
                out[(size_t)row * DD + col] = acc[mt][nt][r] + bsh[col];
            }
}

// ---------------------------------------------------------------------------
extern "C" void kernel_launch(void* const* d_in, const int* in_sizes, int n_in,
                              void* d_out, int out_size, void* d_ws, size_t ws_size,
                              hipStream_t stream) {
    const float* x    = (const float*)d_in[0];
    const int*   adj  = (const int*)d_in[1];
    const float* W    = (const float*)d_in[2];
    const float* bias = (const float*)d_in[3];
    float* out = (float*)d_out;

    // ws layout: xT bf16 8 MB | aggP fp32 NSPLIT x 16 MB | degP fp32 NSPLIT x 64 KB
    unsigned short* xT  = (unsigned short*)d_ws;
    float* aggP = (float*)((char*)d_ws + (size_t)8 * 1024 * 1024);
    float* degP = (float*)((char*)d_ws + (size_t)(8 + 16 * NSPLIT) * 1024 * 1024);

    k_xpose<<<dim3(NR / 64, DD / 64), 256, 0, stream>>>(x, xT);
    k_agg<<<dim3(NR / 64, NSPLIT), 256, 0, stream>>>(adj, xT, aggP, degP);
    k_lin<<<dim3(NR / 64), 256, 0, stream>>>(aggP, degP, W, bias, out);
}